// Round 10
// baseline (7001.081 us; speedup 1.0000x reference)
//
#include <hip/hip_runtime.h>
#include <hip/hip_fp16.h>
#include <cstddef>

#define T_LEN 4096
#define HID 150
#define G4 600
#define NC 300

typedef __attribute__((ext_vector_type(8))) short bf16x8;      // 8 bf16 = 4 VGPRs
typedef __attribute__((ext_vector_type(8))) _Float16 f16x8;    // 8 fp16 = 4 VGPRs
typedef __attribute__((ext_vector_type(4))) float f32x4;

// raw barrier: waits LDS ops only, leaves global loads/stores in flight
__device__ __forceinline__ void barrier_lgkm() {
  asm volatile("s_waitcnt lgkmcnt(0)\n\ts_barrier" ::: "memory");
}

__device__ __forceinline__ float fsig(float x) {
  return __builtin_amdgcn_rcpf(1.f + __expf(-x));
}
__device__ __forceinline__ float ftanh(float x) {
  float ax = fabsf(x);
  float e = __expf(2.f * ax);
  float t = 1.f - 2.f * __builtin_amdgcn_rcpf(e + 1.f);
  return copysignf(t, x);
}
__device__ __forceinline__ unsigned short f2bf(float f) {  // RNE fp32->bf16
  unsigned u = __builtin_bit_cast(unsigned, f);
  u += 0x7fff + ((u >> 16) & 1);
  return (unsigned short)(u >> 16);
}

// ---------------- LSTM scan via MFMA (r11 EXACT - measured best 1780 cyc/step) -
// LEDGER (cyc/step): r3=1814, r5=1854, r6=2439, r7=1968, r8=1893, r9=2361,
// r10=2231, r11=1780 BEST, r12 dist-2=2234, r15 g4-swizzle=1822 (conflicts->0
// but unswizzle cndmasks hit the SERIAL gate phase). r17 v_dot2_f32_f16
// rewrite FAILED correctness (absmax 25) - dot2 semantics on gfx950
// unverified; idea parked pending an instruction probe. Structure FROZEN:
// step = T_matrix(~970, 200 MFMA x 4.85cyc/CU) + T_gate(~450 serial) + sync.
// The 655K bank-conflict counter is explained & benign. DO NOT TOUCH.
template <int W32>
__global__ __launch_bounds__(512, 2) void lstm_scan(
    const float* __restrict__ whh_solv, const float* __restrict__ whh_solu,
    const float* __restrict__ xg_base,
    float* __restrict__ o32v, float* __restrict__ o32u,
    __half* __restrict__ o16v, __half* __restrict__ o16u, int layer)
{
  __shared__ __align__(16) unsigned short h_bf[160];  // bf16 h, zeros beyond 150
  __shared__ __align__(16) float g4[160][4];          // unit-major, gate-minor
  const int c = blockIdx.x;
  const int net = c >> 1, dir = c & 1;
  const float* Whh = (net ? whh_solu : whh_solv) + (size_t)(layer * 2 + dir) * (G4 * HID);
  const float* xg = xg_base + (size_t)c * T_LEN * G4;
  float* out32 = (net ? o32u : o32v) + dir * HID;     // row stride NC (if W32)
  __half* out16 = (net ? o16u : o16v) + dir * HID;    // row stride 320
  const int tid = threadIdx.x;
  const int lane = tid & 63, wv = tid >> 6;
  const int lrow = lane & 15, lq = lane >> 4;  // frag row & k-quad

  // B-fragments, gate-interleaved tiles: T=wv+8j, gt=T&3, uw=T>>2.
  // B[k][lrow] = Whh[gt*150 + (16*uw+lrow)][k]; zero-padded.
  bf16x8 bfr[5][5];  // [j][kk]
#pragma unroll
  for (int j = 0; j < 5; j++) {
    const int T = wv + 8 * j, gt = T & 3, uw = T >> 2;
    const int un = 16 * uw + lrow;
#pragma unroll
    for (int kk = 0; kk < 5; kk++) {
      bf16x8 b;
#pragma unroll
      for (int i = 0; i < 8; i++) {
        const int k = kk * 32 + lq * 8 + i;
        const float v = (un < HID && k < HID) ? Whh[(size_t)(gt * HID + un) * HID + k] : 0.f;
        b[i] = (short)f2bf(v);
      }
      bfr[j][kk] = b;
    }
  }
  if (tid < 160) h_bf[tid] = 0;

  const int t0 = dir ? (T_LEN - 1) : 0;
  const int d16 = dir ? -320 : 320;
  const int d32 = dir ? -NC : NC;
  const int dxg = dir ? -G4 : G4;
  float cst = 0.f;
  float xr0 = 0.f, xr1 = 0.f, xr2 = 0.f, xr3 = 0.f;
  const float* xgp = xg + (size_t)t0 * G4 + tid;   // gate lanes only
  __half* o16p = out16 + (size_t)t0 * 320 + tid;
  float* o32p = out32 + (size_t)t0 * NC + tid;
  if (tid < HID) { xr0 = xgp[0]; xr1 = xgp[HID]; xr2 = xgp[2 * HID]; xr3 = xgp[3 * HID]; }
  barrier_lgkm();

  for (int s = 0; s < T_LEN; s++) {
    // A-frags: row0 = h_bf, rows 1-15 zero -> only lanes with lrow==0 load
    bf16x8 af[5];
#pragma unroll
    for (int kk = 0; kk < 5; kk++) {
      bf16x8 a = {0, 0, 0, 0, 0, 0, 0, 0};
      if (lrow == 0) a = *(const bf16x8*)&h_bf[kk * 32 + lq * 8];
      af[kk] = a;
    }
    f32x4 acc[5];
#pragma unroll
    for (int j = 0; j < 5; j++) acc[j] = (f32x4){0.f, 0.f, 0.f, 0.f};
#pragma unroll
    for (int kk = 0; kk < 5; kk++)
#pragma unroll
      for (int j = 0; j < 5; j++)
        acc[j] = __builtin_amdgcn_mfma_f32_16x16x32_bf16(af[kk], bfr[j][kk], acc[j], 0, 0, 0);
    // D row0 lives in lanes 0-15, reg 0: scatter into unit-major g4.
    if (lane < 16) {
#pragma unroll
      for (int j = 0; j < 5; j++) {
        const int T = wv + 8 * j, gt = T & 3, uw = T >> 2;
        g4[16 * uw + lane][gt] = acc[j][0];
      }
    }
    barrier_lgkm();
    if (tid < HID) {
      const f32x4 g = *(const f32x4*)&g4[tid][0];   // ONE b128, coalesced
      float gi = xr0 + g[0];
      float gf = xr1 + g[1];
      float gg = xr2 + g[2];
      float go = xr3 + g[3];
      xgp += dxg;
      if (s + 1 < T_LEN) {  // prefetch next xg row (stays in flight past barrier)
        xr0 = xgp[0]; xr1 = xgp[HID]; xr2 = xgp[2 * HID]; xr3 = xgp[3 * HID];
      }
      const float iv = fsig(gi), fv = fsig(gf), gv = ftanh(gg), ov = fsig(go);
      cst = fv * cst + iv * gv;
      const float hv = ov * ftanh(cst);
      h_bf[tid] = f2bf(hv);      // matvec input rounded; c/h state stays fp32
      *o16p = __float2half(hv);
      o16p += d16;
      if (W32) { *o32p = hv; o32p += d32; }
    }
    barrier_lgkm();
  }
}

// ---------------- fp32 -> fp16 conversion helpers ------------------------------
// Wihh[8][640][320]: slot s = l*4 + net*2 + dir, zero-padded rows/cols.
// Also zeroes inp[0..639] (the pq_red atomic target) - folded dispatch.
__global__ void conv_w(const float* __restrict__ wv, const float* __restrict__ wu,
                       __half* __restrict__ dst, float* __restrict__ inp)
{
  const int gid = blockIdx.x * 256 + threadIdx.x;
  if (gid < 640) inp[gid] = 0.f;
  if (gid >= 8 * 640 * 320) return;
  const int k = gid % 320, j = (gid / 320) % 640, s = gid / (320 * 640);
  const int l = s >> 2, net = (s >> 1) & 1, dir = s & 1;
  float v = 0.f;
  if (j < G4 && k < NC) {
    const float* src = (net ? wu : wv) + (size_t)(l * 2 + dir) * (G4 * NC);
    v = src[(size_t)j * NC + k];
  }
  dst[gid] = __float2half(v);
}

// X fp32 [4096][300] -> Xh fp16 [4096][320] zero-padded; y selects solv/solu.
// Also zeroes the matching L0vh/L0uh array (scan-0 only writes cols<300).
__global__ void conv_x2(const float* __restrict__ s0, const float* __restrict__ s1,
                        __half* __restrict__ d0, __half* __restrict__ d1,
                        __half* __restrict__ z0, __half* __restrict__ z1)
{
  const int gid = blockIdx.x * 256 + threadIdx.x;
  if (gid >= 4096 * 320) return;
  const float* src = blockIdx.y ? s1 : s0;
  __half* dst = blockIdx.y ? d1 : d0;
  __half* zp = blockIdx.y ? z1 : z0;
  zp[gid] = (__half)0.f;
  const int k = gid % 320, m = gid / 320;
  dst[gid] = __float2half(k < NC ? src[(size_t)m * NC + k] : 0.f);
}

// Xh fp16 [4096][320] -> XT fp16 [320][4096] (rows >= 300 zeroed); y selects H/G.
// Reads the fp16 H/G directly (same value as fp16(fp32 H) - scan wrote both).
__global__ void conv_t2(const __half* __restrict__ s0, const __half* __restrict__ s1,
                        __half* __restrict__ d0, __half* __restrict__ d1)
{
  const int gid = blockIdx.x * 256 + threadIdx.x;
  if (gid >= 320 * 4096) return;
  const __half* src = blockIdx.y ? s1 : s0;
  __half* dst = blockIdx.y ? d1 : d0;
  const int m = gid % 4096, f = gid / 4096;
  dst[gid] = (f < NC) ? src[(size_t)m * 320 + f] : (__half)0.f;
}

// ---------------- xg = X @ Wih^T + b via fp16 MFMA -----------------------------
// grid (64 m-blocks, 4 chains), block 256 (4 waves, 16 rows each). N=640, K=320.
__global__ __launch_bounds__(256) void xg_mfma(
    const __half* __restrict__ Av, const __half* __restrict__ Au,
    const __half* __restrict__ W,   // Wihh + layer*4*640*320
    const float* __restrict__ bihv, const float* __restrict__ bhhv,
    const float* __restrict__ bihu, const float* __restrict__ bhhu,
    float* __restrict__ xg, int layer)
{
  const int tid = threadIdx.x;
  const int lane = tid & 63, wv = tid >> 6;
  const int ln = lane & 15, q = lane >> 4;
  const int chain = blockIdx.y;
  const __half* A = (chain >= 2) ? Au : Av;
  const __half* Wc = W + (size_t)chain * 640 * 320;
  const float* bi = ((chain >= 2) ? bihu : bihv) + (size_t)(layer * 2 + (chain & 1)) * G4;
  const float* bh = ((chain >= 2) ? bhhu : bhhv) + (size_t)(layer * 2 + (chain & 1)) * G4;
  float* C = xg + (size_t)chain * T_LEN * G4;
  const int m0 = blockIdx.x * 64 + wv * 16;
  const __half* Arow = A + (size_t)(m0 + ln) * 320;

  for (int nc = 0; nc < 4; nc++) {       // 4 chunks x 160 cols
    f32x4 acc[10];
#pragma unroll
    for (int j = 0; j < 10; j++) acc[j] = (f32x4){0.f, 0.f, 0.f, 0.f};
    for (int kk = 0; kk < 10; kk++) {
      const f16x8 afr = *(const f16x8*)(Arow + kk * 32 + q * 8);
#pragma unroll
      for (int j = 0; j < 10; j++) {
        const int n = nc * 160 + j * 16 + ln;
        const f16x8 bfr = *(const f16x8*)(Wc + (size_t)n * 320 + kk * 32 + q * 8);
        acc[j] = __builtin_amdgcn_mfma_f32_16x16x32_f16(afr, bfr, acc[j], 0, 0, 0);
      }
    }
#pragma unroll
    for (int j = 0; j < 10; j++) {
      const int n = nc * 160 + j * 16 + ln;
      if (n < G4) {
        const float bias = bi[n] + bh[n];
#pragma unroll
        for (int r = 0; r < 4; r++)
          C[(size_t)(m0 + q * 4 + r) * G4 + n] = acc[j][r] + bias;
      }
    }
  }
}

// ------- S GEMM: AH[m][n] = fp16(Hh[m] . Gh[n]), raw scores (no exp) -----------
// grid (64 m-blocks, 4 n-quadrants), block 256. KEEP 256 blocks (r14 lesson:
// trading grid parallelism for fusion on a minor-traffic kernel costs ~250us).
__global__ __launch_bounds__(256) void s_gemm(
    const __half* __restrict__ Hh, const __half* __restrict__ Gh,
    __half* __restrict__ AH)
{
  const int tid = threadIdx.x;
  const int lane = tid & 63, wv = tid >> 6;
  const int ln = lane & 15, q = lane >> 4;
  const int m0 = blockIdx.x * 64 + wv * 16;
  const __half* Arow = Hh + (size_t)(m0 + ln) * 320;
  f16x8 afr[10];
#pragma unroll
  for (int kk = 0; kk < 10; kk++) afr[kk] = *(const f16x8*)(Arow + kk * 32 + q * 8);
  const int nt0 = blockIdx.y * 64;
  for (int nt = 0; nt < 64; nt++) {
    const int n = 16 * (nt0 + nt) + ln;
    const __half* Brow = Gh + (size_t)n * 320;
    f32x4 acc = (f32x4){0.f, 0.f, 0.f, 0.f};
#pragma unroll
    for (int kk = 0; kk < 10; kk++) {
      const f16x8 bfr = *(const f16x8*)(Brow + kk * 32 + q * 8);
      acc = __builtin_amdgcn_mfma_f32_16x16x32_f16(afr[kk], bfr, acc, 0, 0, 0);
    }
#pragma unroll
    for (int r = 0; r < 4; r++)
      AH[(size_t)(m0 + q * 4 + r) * 4096 + n] = __float2half(acc[r]);
  }
}

// ------- fused softmax: AH[m][:] = fp16( exp(S-30) / sum exp(S-30) ) -----------
// One block per row; the 16 exp values per thread stay in REGISTERS between
// the sum pass and the scale pass -> one HBM read + one write.
__global__ __launch_bounds__(256) void softmax_k(__half* __restrict__ AH)
{
  const int m = blockIdx.x, tid = threadIdx.x;
  __half* row = AH + (size_t)m * 4096;
  float e[16];
  float s = 0.f;
#pragma unroll
  for (int c = 0; c < 2; c++) {
    const f16x8 v = *(const f16x8*)(row + c * 2048 + tid * 8);
#pragma unroll
    for (int j = 0; j < 8; j++) {
      const float ev = __expf(fminf((float)v[j] - 30.f, 80.f));
      e[c * 8 + j] = ev;
      s += ev;
    }
  }
#pragma unroll
  for (int off = 32; off > 0; off >>= 1) s += __shfl_down(s, off);
  __shared__ float red[4];
  if ((tid & 63) == 0) red[tid >> 6] = s;
  __syncthreads();
  const float ilm = 1.f / (red[0] + red[1] + red[2] + red[3]);
#pragma unroll
  for (int c = 0; c < 2; c++) {
    f16x8 v;
#pragma unroll
    for (int j = 0; j < 8; j++) v[j] = (_Float16)(e[c * 8 + j] * ilm);
    *(f16x8*)(row + c * 2048 + tid * 8) = v;
  }
}

// ------- P/Q + reduction fused: 128 blocks -------------------------------------
// P-blocks (0..63): P[m][n] for 64 rows; epilogue computes max(Hb,P) col-sums
// over its rows and atomicAdds into inp[0..299] - P never hits memory.
// Q-blocks (64..127): same with max(Gb,Q) into inp[300..599].
__global__ __launch_bounds__(256) void pq_red(
    const __half* __restrict__ AH, const __half* __restrict__ GhT,
    const __half* __restrict__ HhT,
    const float* __restrict__ Hb, const float* __restrict__ Gb,
    float* __restrict__ inp)
{
  __shared__ __align__(16) _Float16 Ats[64][72];  // qt staging, pitch 144 B
  const int tid = threadIdx.x;
  const int lane = tid & 63, wv = tid >> 6;
  const int ln = lane & 15, q = lane >> 4;

  if (blockIdx.x < 64) {
    // ---- P part: M=4096 rows of AH, N=300, K=4096 ----
    const int m0 = blockIdx.x * 64 + wv * 16;
    const __half* Arow = AH + (size_t)(m0 + ln) * 4096;
    for (int nc = 0; nc < 2; nc++) {
      f32x4 acc[10];
#pragma unroll
      for (int j = 0; j < 10; j++) acc[j] = (f32x4){0.f, 0.f, 0.f, 0.f};
      for (int kk = 0; kk < 128; kk++) {
        const f16x8 afr = *(const f16x8*)(Arow + kk * 32 + q * 8);
#pragma unroll
        for (int j = 0; j < 10; j++) {
          const int n = nc * 160 + j * 16 + ln;
          const f16x8 bfr = *(const f16x8*)(GhT + (size_t)n * 4096 + kk * 32 + q * 8);
          acc[j] = __builtin_amdgcn_mfma_f32_16x16x32_f16(afr, bfr, acc[j], 0, 0, 0);
        }
      }
#pragma unroll
      for (int j = 0; j < 10; j++) {
        const int n = nc * 160 + j * 16 + ln;
        if (n < NC) {
          float sum = 0.f;
#pragma unroll
          for (int r = 0; r < 4; r++)
            sum += fmaxf(Hb[(size_t)(m0 + q * 4 + r) * NC + n], acc[j][r]);
          sum += __shfl_xor(sum, 16);   // combine the 4 q-groups (same col n)
          sum += __shfl_xor(sum, 32);
          if (q == 0) atomicAdd(&inp[n], sum);
        }
      }
    }
  } else {
    // ---- Q part: Q[j][f] = sum_i a[i][j] H[i][f]; a transposed via LDS ----
    const int j0 = (blockIdx.x - 64) * 64;
    f32x4 acc[20];
#pragma unroll
    for (int j = 0; j < 20; j++) acc[j] = (f32x4){0.f, 0.f, 0.f, 0.f};
    const int il8 = tid >> 2, j8 = (tid & 3) * 16;  // staging role
    for (int ic = 0; ic < 4096; ic += 64) {
      __syncthreads();
      {
        const __half* src = AH + (size_t)(ic + il8) * 4096 + j0 + j8;
        const f16x8 v0 = *(const f16x8*)src;
        const f16x8 v1 = *(const f16x8*)(src + 8);
#pragma unroll
        for (int jj = 0; jj < 8; jj++) Ats[j8 + jj][il8] = v0[jj];
#pragma unroll
        for (int jj = 0; jj < 8; jj++) Ats[j8 + 8 + jj][il8] = v1[jj];
      }
      __syncthreads();
#pragma unroll
      for (int s = 0; s < 2; s++) {
        const f16x8 afr = *(const f16x8*)&Ats[wv * 16 + ln][s * 32 + q * 8];
        const __half* bbase = HhT + ic + s * 32 + q * 8;
#pragma unroll
        for (int j = 0; j < 20; j++) {
          const f16x8 bfr = *(const f16x8*)(bbase + (size_t)(j * 16 + ln) * 4096);
          acc[j] = __builtin_amdgcn_mfma_f32_16x16x32_f16(afr, bfr, acc[j], 0, 0, 0);
        }
      }
    }
#pragma unroll
    for (int j = 0; j < 20; j++) {
      const int f = j * 16 + ln;
      if (f < NC) {
        float sum = 0.f;
#pragma unroll
        for (int r = 0; r < 4; r++)
          sum += fmaxf(Gb[(size_t)(j0 + wv * 16 + q * 4 + r) * NC + f], acc[j][r]);
        sum += __shfl_xor(sum, 16);
        sum += __shfl_xor(sum, 32);
        if (q == 0) atomicAdd(&inp[NC + f], sum);
      }
    }
  }
}

// ---------------- tail ---------------------------------------------------------
// wave-per-row: coalesced w1 reads. 500 blocks x 4 waves = 2000 rows.
__global__ __launch_bounds__(256) void fc1_k(
    const float* __restrict__ w1, const float* __restrict__ b1,
    const float* __restrict__ inp, float* __restrict__ x)
{
  const int r = blockIdx.x * 4 + (threadIdx.x >> 6);
  const int lane = threadIdx.x & 63;
  const float* wr = w1 + (size_t)r * 600;
  float s = 0.f;
  for (int k = lane; k < 600; k += 64) s += wr[k] * inp[k];
#pragma unroll
  for (int off = 32; off > 0; off >>= 1) s += __shfl_down(s, off);
  if (lane == 0) x[r] = fmaxf(s + b1[r], 0.f);
}

__global__ void fc2_k(const float* __restrict__ x, const float* __restrict__ w2,
                      const float* __restrict__ b2, float* __restrict__ outp)
{
  const int tid = threadIdx.x;
  float s = 0.f;
  for (int i = tid; i < 2000; i += 256) s += x[i] * w2[i];
#pragma unroll
  for (int off = 32; off > 0; off >>= 1) s += __shfl_down(s, off);
  __shared__ float red[4];
  if ((tid & 63) == 0) red[tid >> 6] = s;
  __syncthreads();
  if (tid == 0) outp[0] = red[0] + red[1] + red[2] + red[3] + b2[0];
}

// ---------------- launch --------------------------------------------------------
extern "C" void kernel_launch(void* const* d_in, const int* in_sizes, int n_in,
                              void* d_out, int out_size, void* d_ws, size_t ws_size,
                              hipStream_t stream)
{
  const float* in_solv  = (const float*)d_in[0];
  const float* in_solu  = (const float*)d_in[1];
  const float* solv_Wih = (const float*)d_in[2];
  const float* solv_Whh = (const float*)d_in[3];
  const float* solv_bih = (const float*)d_in[4];
  const float* solv_bhh = (const float*)d_in[5];
  const float* solu_Wih = (const float*)d_in[6];
  const float* solu_Whh = (const float*)d_in[7];
  const float* solu_bih = (const float*)d_in[8];
  const float* solu_bhh = (const float*)d_in[9];
  const float* fc1_w = (const float*)d_in[10];
  const float* fc1_b = (const float*)d_in[11];
  const float* fc2_w = (const float*)d_in[12];
  const float* fc2_b = (const float*)d_in[13];
  float* outp = (float*)d_out;
  float* ws = (float*)d_ws;

  // ---- workspace layout (float offsets) ----
  constexpr size_t off_P   = 0;         // Wihh fp16 (819,200 fl) - lives all run
  constexpr size_t off_inp = 2457600;   // 640
  constexpr size_t off_x   = 2458240;   // 2048
  constexpr size_t off_xg  = 2468480;   // xg fp32 -> AH fp16 + HhT/GhT fp16
  constexpr size_t off_L0  = off_xg + (size_t)4 * 2457600;   // 12,298,880
  constexpr size_t off_HG  = off_L0 + 1310720;               // 13,609,600

  float*  xg   = ws + off_xg;
  float*  Hb   = ws + off_HG;
  float*  Gb   = Hb + 1228800;
  float*  inp  = ws + off_inp;
  float*  xf   = ws + off_x;
  __half* Wihh = (__half*)(ws + off_P);
  __half* Avh  = (__half*)(ws + off_L0);
  __half* Auh  = Avh + 4096 * 320;
  __half* L0vh = (__half*)(ws + off_HG);
  __half* L0uh = L0vh + 4096 * 320;
  __half* Hh   = (__half*)(ws + off_L0);   // reuses Avh/Auh space (dead)
  __half* Gh   = Hh + 4096 * 320;
  __half* AH   = (__half*)(ws + off_xg);   // after scans (xg dead)
  __half* HhT  = AH + (size_t)4096 * 4096;
  __half* GhT  = HhT + 320 * 4096;

  // ---- prep: convert weights (+zero inp), inputs (+zero L0 pads) ----
  conv_w<<<(8 * 640 * 320 + 255) / 256, 256, 0, stream>>>(solv_Wih, solu_Wih, Wihh, inp);
  conv_x2<<<dim3(5120, 2), 256, 0, stream>>>(in_solv, in_solu, Avh, Auh, L0vh, L0uh);

  // ---- layer 0 (scan writes fp16 L0vh/L0uh directly; no fp32 out) ----
  xg_mfma<<<dim3(64, 4), 256, 0, stream>>>(Avh, Auh, Wihh,
      solv_bih, solv_bhh, solu_bih, solu_bhh, xg, 0);
  lstm_scan<0><<<4, 512, 0, stream>>>(solv_Whh, solu_Whh, xg,
      nullptr, nullptr, L0vh, L0uh, 0);

  // ---- layer 1 (scan writes fp32 Hb/Gb + fp16 Hh/Gh) ----
  xg_mfma<<<dim3(64, 4), 256, 0, stream>>>(L0vh, L0uh, Wihh + (size_t)4 * 640 * 320,
      solv_bih, solv_bhh, solu_bih, solu_bhh, xg, 1);
  lstm_scan<1><<<4, 512, 0, stream>>>(solv_Whh, solu_Whh, xg,
      Hb, Gb, Hh, Gh, 1);

  // ---- attention: transpose (from fp16), S, softmax, P/Q+reduce fused ----
  conv_t2<<<dim3(5120, 2), 256, 0, stream>>>(Hh, Gh, HhT, GhT);
  s_gemm<<<dim3(64, 4), 256, 0, stream>>>(Hh, Gh, AH);
  softmax_k<<<4096, 256, 0, stream>>>(AH);
  pq_red<<<128, 256, 0, stream>>>(AH, GhT, HhT, Hb, Gb, inp);

  // ---- tail ----
  fc1_k<<<500, 256, 0, stream>>>(fc1_w, fc1_b, inp, xf);
  fc2_k<<<1, 256, 0, stream>>>(xf, fc2_w, fc2_b, outp);
}

// Round 12
// 6993.906 us; speedup vs baseline: 1.0010x; 1.0010x over previous
//
#include <hip/hip_runtime.h>
#include <hip/hip_fp16.h>
#include <cstddef>

#define T_LEN 4096
#define HID 150
#define G4 600
#define NC 300

typedef __attribute__((ext_vector_type(8))) short bf16x8;      // 8 bf16 = 4 VGPRs
typedef __attribute__((ext_vector_type(8))) _Float16 f16x8;    // 8 fp16 = 4 VGPRs
typedef __attribute__((ext_vector_type(4))) float f32x4;

// raw barrier: waits LDS ops only, leaves global loads/stores in flight
__device__ __forceinline__ void barrier_lgkm() {
  asm volatile("s_waitcnt lgkmcnt(0)\n\ts_barrier" ::: "memory");
}

__device__ __forceinline__ float fsig(float x) {
  return __builtin_amdgcn_rcpf(1.f + __expf(-x));
}
__device__ __forceinline__ float ftanh(float x) {
  float ax = fabsf(x);
  float e = __expf(2.f * ax);
  float t = 1.f - 2.f * __builtin_amdgcn_rcpf(e + 1.f);
  return copysignf(t, x);
}
__device__ __forceinline__ unsigned short f2bf(float f) {  // RNE fp32->bf16
  unsigned u = __builtin_bit_cast(unsigned, f);
  u += 0x7fff + ((u >> 16) & 1);
  return (unsigned short)(u >> 16);
}

// ---------------- LSTM scan via MFMA (r11 EXACT - measured best 1780 cyc/step) -
// LEDGER (cyc/step): r3=1814, r5=1854, r6=2439, r7=1968, r8=1893, r9=2361,
// r10=2231, r11=1780 BEST, r12 dist-2=2234, r15 g4-swizzle=1822.
// r17/r19 dot-product scans (builtin fdot2 / inline-asm v_dot2_f32_f16)
// FAILED correctness: asm probe proved mapping correct (absmax 25.1->0.5625)
// but residual 2x-over-threshold error is a systematic HW dot-path numerics
// property (biased pair-sum rounding, coherent over the 4096-step
// recurrence) - fp16 inputs are strictly more precise than bf16 yet landed
// 9x worse than r11, ruling out exact-product+fp32-accum semantics. Lead
// CLOSED as HW-infeasible; bf16 dot2 rides the same path - do not retry.
// Structure FROZEN: step = T_matrix(~970, 200 MFMA x 4.85cyc/CU) +
// T_gate(~450 serial) + sync. 655K bank-conflict counter explained & benign.
template <int W32>
__global__ __launch_bounds__(512, 2) void lstm_scan(
    const float* __restrict__ whh_solv, const float* __restrict__ whh_solu,
    const float* __restrict__ xg_base,
    float* __restrict__ o32v, float* __restrict__ o32u,
    __half* __restrict__ o16v, __half* __restrict__ o16u, int layer)
{
  __shared__ __align__(16) unsigned short h_bf[160];  // bf16 h, zeros beyond 150
  __shared__ __align__(16) float g4[160][4];          // unit-major, gate-minor
  const int c = blockIdx.x;
  const int net = c >> 1, dir = c & 1;
  const float* Whh = (net ? whh_solu : whh_solv) + (size_t)(layer * 2 + dir) * (G4 * HID);
  const float* xg = xg_base + (size_t)c * T_LEN * G4;
  float* out32 = (net ? o32u : o32v) + dir * HID;     // row stride NC (if W32)
  __half* out16 = (net ? o16u : o16v) + dir * HID;    // row stride 320
  const int tid = threadIdx.x;
  const int lane = tid & 63, wv = tid >> 6;
  const int lrow = lane & 15, lq = lane >> 4;  // frag row & k-quad

  // B-fragments, gate-interleaved tiles: T=wv+8j, gt=T&3, uw=T>>2.
  // B[k][lrow] = Whh[gt*150 + (16*uw+lrow)][k]; zero-padded.
  bf16x8 bfr[5][5];  // [j][kk]
#pragma unroll
  for (int j = 0; j < 5; j++) {
    const int T = wv + 8 * j, gt = T & 3, uw = T >> 2;
    const int un = 16 * uw + lrow;
#pragma unroll
    for (int kk = 0; kk < 5; kk++) {
      bf16x8 b;
#pragma unroll
      for (int i = 0; i < 8; i++) {
        const int k = kk * 32 + lq * 8 + i;
        const float v = (un < HID && k < HID) ? Whh[(size_t)(gt * HID + un) * HID + k] : 0.f;
        b[i] = (short)f2bf(v);
      }
      bfr[j][kk] = b;
    }
  }
  if (tid < 160) h_bf[tid] = 0;

  const int t0 = dir ? (T_LEN - 1) : 0;
  const int d16 = dir ? -320 : 320;
  const int d32 = dir ? -NC : NC;
  const int dxg = dir ? -G4 : G4;
  float cst = 0.f;
  float xr0 = 0.f, xr1 = 0.f, xr2 = 0.f, xr3 = 0.f;
  const float* xgp = xg + (size_t)t0 * G4 + tid;   // gate lanes only
  __half* o16p = out16 + (size_t)t0 * 320 + tid;
  float* o32p = out32 + (size_t)t0 * NC + tid;
  if (tid < HID) { xr0 = xgp[0]; xr1 = xgp[HID]; xr2 = xgp[2 * HID]; xr3 = xgp[3 * HID]; }
  barrier_lgkm();

  for (int s = 0; s < T_LEN; s++) {
    // A-frags: row0 = h_bf, rows 1-15 zero -> only lanes with lrow==0 load
    bf16x8 af[5];
#pragma unroll
    for (int kk = 0; kk < 5; kk++) {
      bf16x8 a = {0, 0, 0, 0, 0, 0, 0, 0};
      if (lrow == 0) a = *(const bf16x8*)&h_bf[kk * 32 + lq * 8];
      af[kk] = a;
    }
    f32x4 acc[5];
#pragma unroll
    for (int j = 0; j < 5; j++) acc[j] = (f32x4){0.f, 0.f, 0.f, 0.f};
#pragma unroll
    for (int kk = 0; kk < 5; kk++)
#pragma unroll
      for (int j = 0; j < 5; j++)
        acc[j] = __builtin_amdgcn_mfma_f32_16x16x32_bf16(af[kk], bfr[j][kk], acc[j], 0, 0, 0);
    // D row0 lives in lanes 0-15, reg 0: scatter into unit-major g4.
    if (lane < 16) {
#pragma unroll
      for (int j = 0; j < 5; j++) {
        const int T = wv + 8 * j, gt = T & 3, uw = T >> 2;
        g4[16 * uw + lane][gt] = acc[j][0];
      }
    }
    barrier_lgkm();
    if (tid < HID) {
      const f32x4 g = *(const f32x4*)&g4[tid][0];   // ONE b128, coalesced
      float gi = xr0 + g[0];
      float gf = xr1 + g[1];
      float gg = xr2 + g[2];
      float go = xr3 + g[3];
      xgp += dxg;
      if (s + 1 < T_LEN) {  // prefetch next xg row (stays in flight past barrier)
        xr0 = xgp[0]; xr1 = xgp[HID]; xr2 = xgp[2 * HID]; xr3 = xgp[3 * HID];
      }
      const float iv = fsig(gi), fv = fsig(gf), gv = ftanh(gg), ov = fsig(go);
      cst = fv * cst + iv * gv;
      const float hv = ov * ftanh(cst);
      h_bf[tid] = f2bf(hv);      // matvec input rounded; c/h state stays fp32
      *o16p = __float2half(hv);
      o16p += d16;
      if (W32) { *o32p = hv; o32p += d32; }
    }
    barrier_lgkm();
  }
}

// ---------------- fp32 -> fp16 conversion helpers ------------------------------
// Wihh[8][640][320]: slot s = l*4 + net*2 + dir, zero-padded rows/cols.
// Also zeroes inp[0..639] (the pq_red atomic target) - folded dispatch.
__global__ void conv_w(const float* __restrict__ wv, const float* __restrict__ wu,
                       __half* __restrict__ dst, float* __restrict__ inp)
{
  const int gid = blockIdx.x * 256 + threadIdx.x;
  if (gid < 640) inp[gid] = 0.f;
  if (gid >= 8 * 640 * 320) return;
  const int k = gid % 320, j = (gid / 320) % 640, s = gid / (320 * 640);
  const int l = s >> 2, net = (s >> 1) & 1, dir = s & 1;
  float v = 0.f;
  if (j < G4 && k < NC) {
    const float* src = (net ? wu : wv) + (size_t)(l * 2 + dir) * (G4 * NC);
    v = src[(size_t)j * NC + k];
  }
  dst[gid] = __float2half(v);
}

// X fp32 [4096][300] -> Xh fp16 [4096][320] zero-padded; y selects solv/solu.
// Also zeroes the matching L0vh/L0uh array (scan-0 only writes cols<300).
__global__ void conv_x2(const float* __restrict__ s0, const float* __restrict__ s1,
                        __half* __restrict__ d0, __half* __restrict__ d1,
                        __half* __restrict__ z0, __half* __restrict__ z1)
{
  const int gid = blockIdx.x * 256 + threadIdx.x;
  if (gid >= 4096 * 320) return;
  const float* src = blockIdx.y ? s1 : s0;
  __half* dst = blockIdx.y ? d1 : d0;
  __half* zp = blockIdx.y ? z1 : z0;
  zp[gid] = (__half)0.f;
  const int k = gid % 320, m = gid / 320;
  dst[gid] = __float2half(k < NC ? src[(size_t)m * NC + k] : 0.f);
}

// Xh fp16 [4096][320] -> XT fp16 [320][4096] (rows >= 300 zeroed); y selects H/G.
// Reads the fp16 H/G directly (same value as fp16(fp32 H) - scan wrote both).
__global__ void conv_t2(const __half* __restrict__ s0, const __half* __restrict__ s1,
                        __half* __restrict__ d0, __half* __restrict__ d1)
{
  const int gid = blockIdx.x * 256 + threadIdx.x;
  if (gid >= 320 * 4096) return;
  const __half* src = blockIdx.y ? s1 : s0;
  __half* dst = blockIdx.y ? d1 : d0;
  const int m = gid % 4096, f = gid / 4096;
  dst[gid] = (f < NC) ? src[(size_t)m * 320 + f] : (__half)0.f;
}

// ---------------- xg = X @ Wih^T + b via fp16 MFMA -----------------------------
// grid (64 m-blocks, 4 chains), block 256 (4 waves, 16 rows each). N=640, K=320.
__global__ __launch_bounds__(256) void xg_mfma(
    const __half* __restrict__ Av, const __half* __restrict__ Au,
    const __half* __restrict__ W,   // Wihh + layer*4*640*320
    const float* __restrict__ bihv, const float* __restrict__ bhhv,
    const float* __restrict__ bihu, const float* __restrict__ bhhu,
    float* __restrict__ xg, int layer)
{
  const int tid = threadIdx.x;
  const int lane = tid & 63, wv = tid >> 6;
  const int ln = lane & 15, q = lane >> 4;
  const int chain = blockIdx.y;
  const __half* A = (chain >= 2) ? Au : Av;
  const __half* Wc = W + (size_t)chain * 640 * 320;
  const float* bi = ((chain >= 2) ? bihu : bihv) + (size_t)(layer * 2 + (chain & 1)) * G4;
  const float* bh = ((chain >= 2) ? bhhu : bhhv) + (size_t)(layer * 2 + (chain & 1)) * G4;
  float* C = xg + (size_t)chain * T_LEN * G4;
  const int m0 = blockIdx.x * 64 + wv * 16;
  const __half* Arow = A + (size_t)(m0 + ln) * 320;

  for (int nc = 0; nc < 4; nc++) {       // 4 chunks x 160 cols
    f32x4 acc[10];
#pragma unroll
    for (int j = 0; j < 10; j++) acc[j] = (f32x4){0.f, 0.f, 0.f, 0.f};
    for (int kk = 0; kk < 10; kk++) {
      const f16x8 afr = *(const f16x8*)(Arow + kk * 32 + q * 8);
#pragma unroll
      for (int j = 0; j < 10; j++) {
        const int n = nc * 160 + j * 16 + ln;
        const f16x8 bfr = *(const f16x8*)(Wc + (size_t)n * 320 + kk * 32 + q * 8);
        acc[j] = __builtin_amdgcn_mfma_f32_16x16x32_f16(afr, bfr, acc[j], 0, 0, 0);
      }
    }
#pragma unroll
    for (int j = 0; j < 10; j++) {
      const int n = nc * 160 + j * 16 + ln;
      if (n < G4) {
        const float bias = bi[n] + bh[n];
#pragma unroll
        for (int r = 0; r < 4; r++)
          C[(size_t)(m0 + q * 4 + r) * G4 + n] = acc[j][r] + bias;
      }
    }
  }
}

// ------- S GEMM: AH[m][n] = fp16(Hh[m] . Gh[n]), raw scores (no exp) -----------
// grid (64 m-blocks, 4 n-quadrants), block 256. KEEP 256 blocks (r14 lesson:
// trading grid parallelism for fusion on a minor-traffic kernel costs ~250us).
__global__ __launch_bounds__(256) void s_gemm(
    const __half* __restrict__ Hh, const __half* __restrict__ Gh,
    __half* __restrict__ AH)
{
  const int tid = threadIdx.x;
  const int lane = tid & 63, wv = tid >> 6;
  const int ln = lane & 15, q = lane >> 4;
  const int m0 = blockIdx.x * 64 + wv * 16;
  const __half* Arow = Hh + (size_t)(m0 + ln) * 320;
  f16x8 afr[10];
#pragma unroll
  for (int kk = 0; kk < 10; kk++) afr[kk] = *(const f16x8*)(Arow + kk * 32 + q * 8);
  const int nt0 = blockIdx.y * 64;
  for (int nt = 0; nt < 64; nt++) {
    const int n = 16 * (nt0 + nt) + ln;
    const __half* Brow = Gh + (size_t)n * 320;
    f32x4 acc = (f32x4){0.f, 0.f, 0.f, 0.f};
#pragma unroll
    for (int kk = 0; kk < 10; kk++) {
      const f16x8 bfr = *(const f16x8*)(Brow + kk * 32 + q * 8);
      acc = __builtin_amdgcn_mfma_f32_16x16x32_f16(afr[kk], bfr, acc, 0, 0, 0);
    }
#pragma unroll
    for (int r = 0; r < 4; r++)
      AH[(size_t)(m0 + q * 4 + r) * 4096 + n] = __float2half(acc[r]);
  }
}

// ------- fused softmax: AH[m][:] = fp16( exp(S-30) / sum exp(S-30) ) -----------
// One block per row; the 16 exp values per thread stay in REGISTERS between
// the sum pass and the scale pass -> one HBM read + one write.
__global__ __launch_bounds__(256) void softmax_k(__half* __restrict__ AH)
{
  const int m = blockIdx.x, tid = threadIdx.x;
  __half* row = AH + (size_t)m * 4096;
  float e[16];
  float s = 0.f;
#pragma unroll
  for (int c = 0; c < 2; c++) {
    const f16x8 v = *(const f16x8*)(row + c * 2048 + tid * 8);
#pragma unroll
    for (int j = 0; j < 8; j++) {
      const float ev = __expf(fminf((float)v[j] - 30.f, 80.f));
      e[c * 8 + j] = ev;
      s += ev;
    }
  }
#pragma unroll
  for (int off = 32; off > 0; off >>= 1) s += __shfl_down(s, off);
  __shared__ float red[4];
  if ((tid & 63) == 0) red[tid >> 6] = s;
  __syncthreads();
  const float ilm = 1.f / (red[0] + red[1] + red[2] + red[3]);
#pragma unroll
  for (int c = 0; c < 2; c++) {
    f16x8 v;
#pragma unroll
    for (int j = 0; j < 8; j++) v[j] = (_Float16)(e[c * 8 + j] * ilm);
    *(f16x8*)(row + c * 2048 + tid * 8) = v;
  }
}

// ------- P/Q + reduction fused: 128 blocks -------------------------------------
// P-blocks (0..63): P[m][n] for 64 rows; epilogue computes max(Hb,P) col-sums
// over its rows and atomicAdds into inp[0..299] - P never hits memory.
// Q-blocks (64..127): same with max(Gb,Q) into inp[300..599].
__global__ __launch_bounds__(256) void pq_red(
    const __half* __restrict__ AH, const __half* __restrict__ GhT,
    const __half* __restrict__ HhT,
    const float* __restrict__ Hb, const float* __restrict__ Gb,
    float* __restrict__ inp)
{
  __shared__ __align__(16) _Float16 Ats[64][72];  // qt staging, pitch 144 B
  const int tid = threadIdx.x;
  const int lane = tid & 63, wv = tid >> 6;
  const int ln = lane & 15, q = lane >> 4;

  if (blockIdx.x < 64) {
    // ---- P part: M=4096 rows of AH, N=300, K=4096 ----
    const int m0 = blockIdx.x * 64 + wv * 16;
    const __half* Arow = AH + (size_t)(m0 + ln) * 4096;
    for (int nc = 0; nc < 2; nc++) {
      f32x4 acc[10];
#pragma unroll
      for (int j = 0; j < 10; j++) acc[j] = (f32x4){0.f, 0.f, 0.f, 0.f};
      for (int kk = 0; kk < 128; kk++) {
        const f16x8 afr = *(const f16x8*)(Arow + kk * 32 + q * 8);
#pragma unroll
        for (int j = 0; j < 10; j++) {
          const int n = nc * 160 + j * 16 + ln;
          const f16x8 bfr = *(const f16x8*)(GhT + (size_t)n * 4096 + kk * 32 + q * 8);
          acc[j] = __builtin_amdgcn_mfma_f32_16x16x32_f16(afr, bfr, acc[j], 0, 0, 0);
        }
      }
#pragma unroll
      for (int j = 0; j < 10; j++) {
        const int n = nc * 160 + j * 16 + ln;
        if (n < NC) {
          float sum = 0.f;
#pragma unroll
          for (int r = 0; r < 4; r++)
            sum += fmaxf(Hb[(size_t)(m0 + q * 4 + r) * NC + n], acc[j][r]);
          sum += __shfl_xor(sum, 16);   // combine the 4 q-groups (same col n)
          sum += __shfl_xor(sum, 32);
          if (q == 0) atomicAdd(&inp[n], sum);
        }
      }
    }
  } else {
    // ---- Q part: Q[j][f] = sum_i a[i][j] H[i][f]; a transposed via LDS ----
    const int j0 = (blockIdx.x - 64) * 64;
    f32x4 acc[20];
#pragma unroll
    for (int j = 0; j < 20; j++) acc[j] = (f32x4){0.f, 0.f, 0.f, 0.f};
    const int il8 = tid >> 2, j8 = (tid & 3) * 16;  // staging role
    for (int ic = 0; ic < 4096; ic += 64) {
      __syncthreads();
      {
        const __half* src = AH + (size_t)(ic + il8) * 4096 + j0 + j8;
        const f16x8 v0 = *(const f16x8*)src;
        const f16x8 v1 = *(const f16x8*)(src + 8);
#pragma unroll
        for (int jj = 0; jj < 8; jj++) Ats[j8 + jj][il8] = v0[jj];
#pragma unroll
        for (int jj = 0; jj < 8; jj++) Ats[j8 + 8 + jj][il8] = v1[jj];
      }
      __syncthreads();
#pragma unroll
      for (int s = 0; s < 2; s++) {
        const f16x8 afr = *(const f16x8*)&Ats[wv * 16 + ln][s * 32 + q * 8];
        const __half* bbase = HhT + ic + s * 32 + q * 8;
#pragma unroll
        for (int j = 0; j < 20; j++) {
          const f16x8 bfr = *(const f16x8*)(bbase + (size_t)(j * 16 + ln) * 4096);
          acc[j] = __builtin_amdgcn_mfma_f32_16x16x32_f16(afr, bfr, acc[j], 0, 0, 0);
        }
      }
    }
#pragma unroll
    for (int j = 0; j < 20; j++) {
      const int f = j * 16 + ln;
      if (f < NC) {
        float sum = 0.f;
#pragma unroll
        for (int r = 0; r < 4; r++)
          sum += fmaxf(Gb[(size_t)(j0 + wv * 16 + q * 4 + r) * NC + f], acc[j][r]);
        sum += __shfl_xor(sum, 16);
        sum += __shfl_xor(sum, 32);
        if (q == 0) atomicAdd(&inp[NC + f], sum);
      }
    }
  }
}

// ---------------- tail ---------------------------------------------------------
// wave-per-row: coalesced w1 reads. 500 blocks x 4 waves = 2000 rows.
__global__ __launch_bounds__(256) void fc1_k(
    const float* __restrict__ w1, const float* __restrict__ b1,
    const float* __restrict__ inp, float* __restrict__ x)
{
  const int r = blockIdx.x * 4 + (threadIdx.x >> 6);
  const int lane = threadIdx.x & 63;
  const float* wr = w1 + (size_t)r * 600;
  float s = 0.f;
  for (int k = lane; k < 600; k += 64) s += wr[k] * inp[k];
#pragma unroll
  for (int off = 32; off > 0; off >>= 1) s += __shfl_down(s, off);
  if (lane == 0) x[r] = fmaxf(s + b1[r], 0.f);
}

__global__ void fc2_k(const float* __restrict__ x, const float* __restrict__ w2,
                      const float* __restrict__ b2, float* __restrict__ outp)
{
  const int tid = threadIdx.x;
  float s = 0.f;
  for (int i = tid; i < 2000; i += 256) s += x[i] * w2[i];
#pragma unroll
  for (int off = 32; off > 0; off >>= 1) s += __shfl_down(s, off);
  __shared__ float red[4];
  if ((tid & 63) == 0) red[tid >> 6] = s;
  __syncthreads();
  if (tid == 0) outp[0] = red[0] + red[1] + red[2] + red[3] + b2[0];
}

// ---------------- launch --------------------------------------------------------
extern "C" void kernel_launch(void* const* d_in, const int* in_sizes, int n_in,
                              void* d_out, int out_size, void* d_ws, size_t ws_size,
                              hipStream_t stream)
{
  const float* in_solv  = (const float*)d_in[0];
  const float* in_solu  = (const float*)d_in[1];
  const float* solv_Wih = (const float*)d_in[2];
  const float* solv_Whh = (const float*)d_in[3];
  const float* solv_bih = (const float*)d_in[4];
  const float* solv_bhh = (const float*)d_in[5];
  const float* solu_Wih = (const float*)d_in[6];
  const float* solu_Whh = (const float*)d_in[7];
  const float* solu_bih = (const float*)d_in[8];
  const float* solu_bhh = (const float*)d_in[9];
  const float* fc1_w = (const float*)d_in[10];
  const float* fc1_b = (const float*)d_in[11];
  const float* fc2_w = (const float*)d_in[12];
  const float* fc2_b = (const float*)d_in[13];
  float* outp = (float*)d_out;
  float* ws = (float*)d_ws;

  // ---- workspace layout (float offsets) ----
  constexpr size_t off_P   = 0;         // Wihh fp16 (819,200 fl) - lives all run
  constexpr size_t off_inp = 2457600;   // 640
  constexpr size_t off_x   = 2458240;   // 2048
  constexpr size_t off_xg  = 2468480;   // xg fp32 -> AH fp16 + HhT/GhT fp16
  constexpr size_t off_L0  = off_xg + (size_t)4 * 2457600;   // 12,298,880
  constexpr size_t off_HG  = off_L0 + 1310720;               // 13,609,600

  float*  xg   = ws + off_xg;
  float*  Hb   = ws + off_HG;
  float*  Gb   = Hb + 1228800;
  float*  inp  = ws + off_inp;
  float*  xf   = ws + off_x;
  __half* Wihh = (__half*)(ws + off_P);
  __half* Avh  = (__half*)(ws + off_L0);
  __half* Auh  = Avh + 4096 * 320;
  __half* L0vh = (__half*)(ws + off_HG);
  __half* L0uh = L0vh + 4096 * 320;
  __half* Hh   = (__half*)(ws + off_L0);   // reuses Avh/Auh space (dead)
  __half* Gh   = Hh + 4096 * 320;
  __half* AH   = (__half*)(ws + off_xg);   // after scans (xg dead)
  __half* HhT  = AH + (size_t)4096 * 4096;
  __half* GhT  = HhT + 320 * 4096;

  // ---- prep: convert weights (+zero inp), inputs (+zero L0 pads) ----
  conv_w<<<(8 * 640 * 320 + 255) / 256, 256, 0, stream>>>(solv_Wih, solu_Wih, Wihh, inp);
  conv_x2<<<dim3(5120, 2), 256, 0, stream>>>(in_solv, in_solu, Avh, Auh, L0vh, L0uh);

  // ---- layer 0 (scan writes fp16 L0vh/L0uh directly; no fp32 out) ----
  xg_mfma<<<dim3(64, 4), 256, 0, stream>>>(Avh, Auh, Wihh,
      solv_bih, solv_bhh, solu_bih, solu_bhh, xg, 0);
  lstm_scan<0><<<4, 512, 0, stream>>>(solv_Whh, solu_Whh, xg,
      nullptr, nullptr, L0vh, L0uh, 0);

  // ---- layer 1 (scan writes fp32 Hb/Gb + fp16 Hh/Gh) ----
  xg_mfma<<<dim3(64, 4), 256, 0, stream>>>(L0vh, L0uh, Wihh + (size_t)4 * 640 * 320,
      solv_bih, solv_bhh, solu_bih, solu_bhh, xg, 1);
  lstm_scan<1><<<4, 512, 0, stream>>>(solv_Whh, solu_Whh, xg,
      Hb, Gb, Hh, Gh, 1);

  // ---- attention: transpose (from fp16), S, softmax, P/Q+reduce fused ----
  conv_t2<<<dim3(5120, 2), 256, 0, stream>>>(Hh, Gh, HhT, GhT);
  s_gemm<<<dim3(64, 4), 256, 0, stream>>>(Hh, Gh, AH);
  softmax_k<<<4096, 256, 0, stream>>>(AH);
  pq_red<<<128, 256, 0, stream>>>(AH, GhT, HhT, Hb, Gb, inp);

  // ---- tail ----
  fc1_k<<<500, 256, 0, stream>>>(fc1_w, fc1_b, inp, xf);
  fc2_k<<<1, 256, 0, stream>>>(xf, fc2_w, fc2_b, outp);
}